// Round 6
// baseline (126.050 us; speedup 1.0000x reference)
//
#include <hip/hip_runtime.h>
#include <math.h>

// KDE log-density: out[i] = log(1e-8 + (1/N) * sum_j exp(t1 - 50*||xe_i - xb_j||^2))
// N = 16384, D = 16, fp32 in/out.
//
// Round 11: round-9 base (best known, 66.6 us) + two micro-edits.
//  - Round-10 post-mortem: fusing conversion into main was 64x-redundant
//    (each m-block re-converts the same j-slice) -> +3.2 us. Reverted.
//    kde_pre's one-time conversion amortizes over 64 blocks; it stays.
//  - Edit 1: flat inner loop, every ds_read = base + compile-time immediate
//    offset (no manual prefetch/peel — pointless against LDS latency; let
//    the compiler schedule).
//  - Edit 2: slice-min screen. One wave-uniform thrmin = min over the
//    block's 1024 per-col thresholds (shfl-reduced during staging) replaces
//    the per-tile per-col thr ds_read. thrmin <= thr[col] -> strictly more
//    conservative, zero false negatives; rare path reads the exact per-col
//    pbthr from global (cold) so hit numerics are bit-identical.
//  - kde_pre, screen tree, rare exp/atomicAdd/atomicMin path: unchanged.

#define KDE_N 16384
#define KDE_D 16
#define MT 32                  // rows per wave m-tile
#define MWAVES 8               // waves per block
#define MB (MT * MWAVES)       // 256 eval rows per block
#define JSPLIT 16
#define JTILES (KDE_N / 32 / JSPLIT)   // 32 j-tiles per wave
#define THR (-135.0f)          // log2-domain underflow screen

typedef __attribute__((ext_vector_type(8)))  short   short8;
typedef __attribute__((ext_vector_type(16))) float   float16_t;

__device__ __forceinline__ unsigned short f32_to_bf16_rne(float f) {
    unsigned int u = __float_as_uint(f);
    unsigned int r = (u + 0x7FFFu + ((u >> 16) & 1u)) >> 16;
    return (unsigned short)r;
}

// ---- prologue: pe / (THR - pb), scaled bf16 casts, zero S, default out ----
__global__ void kde_pre(const float* __restrict__ xe, const float* __restrict__ xb,
                        float* __restrict__ S, float* __restrict__ pe,
                        float* __restrict__ pbthr, unsigned short* __restrict__ xe16,
                        unsigned short* __restrict__ xb16, float* __restrict__ out)
{
    const int t = blockIdx.x * blockDim.x + threadIdx.x;   // 0..32767
    const int row = t & (KDE_N - 1);
    const bool isB = t >= KDE_N;
    const float* src = (isB ? xb : xe) + (size_t)row * KDE_D;
    const float4* s4 = (const float4*)src;
    const float SQSC = 12.011224664550577f;   // sqrt(100*log2e)
    float q = 0.f;
    unsigned int w[8];
    #pragma unroll
    for (int k = 0; k < 4; ++k) {
        float4 v = s4[k];
        q += v.x*v.x + v.y*v.y + v.z*v.z + v.w*v.w;
        w[2*k+0] = (unsigned int)f32_to_bf16_rne(v.x * SQSC)
                 | ((unsigned int)f32_to_bf16_rne(v.y * SQSC) << 16);
        w[2*k+1] = (unsigned int)f32_to_bf16_rne(v.z * SQSC)
                 | ((unsigned int)f32_to_bf16_rne(v.w * SQSC) << 16);
    }
    unsigned short* dst = (isB ? xb16 : xe16) + (size_t)row * KDE_D;
    uint4* d4 = (uint4*)dst;
    d4[0] = make_uint4(w[0], w[1], w[2], w[3]);
    d4[1] = make_uint4(w[4], w[5], w[6], w[7]);
    const float T1L2E  = -17.8920067984f;       // log2e * t1
    const float C72    = 72.134752044447963f;   // 50 * log2e
    const float LOG1EM8 = -18.420680743952367f; // log(1e-8)
    if (!isB) { pe[row] = T1L2E - C72 * q; S[row] = 0.f; out[row] = LOG1EM8; }
    else      { pbthr[row] = THR + C72 * q; }   // THR - pb,  pb = -C72*b2
}

// ---- main: LDS-staged B + flat MFMA loop + slice-min screen ----
__global__ __launch_bounds__(512, 8) void kde_main(
    const unsigned short* __restrict__ xe16, const unsigned short* __restrict__ xb16,
    const float* __restrict__ pe, const float* __restrict__ pbthr,
    float* __restrict__ S, float* __restrict__ out)
{
    // smem: B-slice bf16 [1024 rows x 32 B] = 32768 | wavemin[8] f32 (+pad)
    __shared__ char smem[32768 + 64];

    const int tid  = threadIdx.x;
    const int lane = tid & 63;
    const int wave = tid >> 6;                      // 0..7
    const int m0   = blockIdx.y * MB + wave * MT;
    const int jt0  = blockIdx.x * JTILES;           // j-tile base (fast dim)

    // ---- stage B-slice (32 KB) into LDS; contiguous 16 B/lane ----
    {
        const char* gsrc = (const char*)xb16 + (size_t)jt0 * 32 * KDE_D * sizeof(short);
        #pragma unroll
        for (int k = 0; k < 4; ++k) {
            const int off = k * 8192 + tid * 16;
            *(uint4*)(smem + off) = *(const uint4*)(gsrc + off);
        }
    }
    // ---- slice-min of the 1024 per-col thresholds (wave shfl reduce) ----
    {
        const float* tsl = pbthr + jt0 * 32;
        float tmin = fminf(tsl[tid], tsl[tid + 512]);
        #pragma unroll
        for (int s = 1; s < 64; s <<= 1)
            tmin = fminf(tmin, __shfl_xor(tmin, s));
        if (lane == 0) *(float*)(smem + 32768 + wave * 4) = tmin;
    }

    const int col  = lane & 31;   // A row / B col / C col
    const int half = lane >> 5;   // k-half for A/B frags; row-group for C

    // A fragment, loaded once (K=16 == D)
    const short8 af = *(const short8*)(xe16 + (size_t)(m0 + col) * KDE_D + half * 8);

    // C operand = pe for the 16 C rows this lane owns:
    // row(r) = (r&3) + 8*(r>>2) + 4*half  -> 4 contiguous quads at +0/+8/+16/+24
    const float4* pq = (const float4*)(pe + m0 + 4 * half);
    const float4 q0 = pq[0], q1 = pq[2], q2 = pq[4], q3 = pq[6];
    float16_t perv;
    perv[0]=q0.x;  perv[1]=q0.y;  perv[2]=q0.z;  perv[3]=q0.w;
    perv[4]=q1.x;  perv[5]=q1.y;  perv[6]=q1.z;  perv[7]=q1.w;
    perv[8]=q2.x;  perv[9]=q2.y;  perv[10]=q2.z; perv[11]=q2.w;
    perv[12]=q3.x; perv[13]=q3.y; perv[14]=q3.z; perv[15]=q3.w;

    const float INVN = 1.0f / (float)KDE_N;

    __syncthreads();   // B-slice + wave mins resident

    // block-wide threshold min (broadcast reads, conflict-free)
    const float4 wm0 = *(const float4*)(smem + 32768);
    const float4 wm1 = *(const float4*)(smem + 32768 + 16);
    const float thrmin = fminf(fminf(fminf(wm0.x, wm0.y), fminf(wm0.z, wm0.w)),
                               fminf(fminf(wm1.x, wm1.y), fminf(wm1.z, wm1.w)));

    // rare hit path: exact per-col threshold from global (cold), numerics
    // identical to round 9's in-loop path
    auto rare = [&](const float16_t& d, int t) {
        const float pbv = THR - pbthr[(jt0 + t) * 32 + col];
        #pragma unroll
        for (int r = 0; r < 16; ++r) {
            float e = exp2f(d[r] + pbv);
            if (e != 0.f) {
                const int row = m0 + (r & 3) + 8 * (r >> 2) + 4 * half;
                float old  = atomicAdd(&S[row], e);
                float cand = logf(1e-8f + (old + e) * INVN);
                // all cands negative: float-max == uint-min on raw bits
                atomicMin((unsigned int*)&out[row], __float_as_uint(cand));
            }
        }
    };

    // ---- flat loop: every LDS read is base + compile-time immediate ----
    const char* bbase = smem + col * 32 + half * 16;
    #pragma unroll 8
    for (int t = 0; t < JTILES; ++t) {
        const short8 bf = *(const short8*)(bbase + t * 1024);
        const float16_t d = __builtin_amdgcn_mfma_f32_32x32x16_bf16(af, bf, perv, 0, 0, 0);
        // max over this lane's 16 values, max3-friendly shape
        float m1 = fmaxf(fmaxf(d[0],  d[1]),  d[2]);
        float m2 = fmaxf(fmaxf(d[3],  d[4]),  d[5]);
        float m3 = fmaxf(fmaxf(d[6],  d[7]),  d[8]);
        float m4 = fmaxf(fmaxf(d[9],  d[10]), d[11]);
        float m5 = fmaxf(fmaxf(d[12], d[13]), d[14]);
        float x  = fmaxf(fmaxf(m1, m2), m3);
        float y  = fmaxf(fmaxf(m4, m5), d[15]);
        float mx = fmaxf(x, y);
        if (__any(mx > thrmin)) rare(d, t);   // conservative, ~never taken
    }
}

extern "C" void kernel_launch(void* const* d_in, const int* in_sizes, int n_in,
                              void* d_out, int out_size, void* d_ws, size_t ws_size,
                              hipStream_t stream)
{
    const float* xe = (const float*)d_in[0];  // x_eval [16384,16] fp32
    const float* xb = (const float*)d_in[1];  // x_base [16384,16] fp32
    float* out = (float*)d_out;

    // ws layout: S[16384] | pe[16384] | pbthr[16384] | xe16 | xb16
    float* S     = (float*)d_ws;
    float* pe    = S + KDE_N;
    float* pbthr = pe + KDE_N;
    unsigned short* xe16 = (unsigned short*)(pbthr + KDE_N);
    unsigned short* xb16 = xe16 + (size_t)KDE_N * KDE_D;

    kde_pre<<<(2 * KDE_N) / 256, 256, 0, stream>>>(xe, xb, S, pe, pbthr, xe16, xb16, out);
    dim3 grid(JSPLIT, KDE_N / MB);   // (16, 64) = 1024 blocks = 4/CU, resident
    kde_main<<<grid, MWAVES * 64, 0, stream>>>(xe16, xb16, pe, pbthr, S, out);
}

// Round 7
// 68.224 us; speedup vs baseline: 1.8476x; 1.8476x over previous
//
#include <hip/hip_runtime.h>
#include <math.h>

// KDE log-density: out[i] = log(1e-8 + (1/N) * sum_j exp(t1 - 50*||xe_i - xb_j||^2))
// N = 16384, D = 16, fp32 in/out.
//
// Round 12: round-9 base (best known, 66.6 us) + LDS XOR-swizzle + B-only pre.
//  - Round-11 post-mortem: slice-min screen lost ~900 log2-units of margin
//    (thrmin = min over 1024 chi2(16) thresholds) -> rare path ran on ~every
//    tile (VALUBusy 88%, kde_main 78 us). REVERTED to per-col thresholds.
//    Counters also showed SQ_LDS_BANK_CONFLICT = 2^20 = 4 extra cyc per
//    ds_read_b128: col*32 row stride is an 8-way bank alias (round 9 too).
//  - Edit 1: XOR-swizzle B tiles in LDS: off ^= ((off>>7)&7)<<4 permutes
//    16B granules within each 1KB tile (involution; applied on BOTH the
//    staging write and the read base). Even bank spread -> ~0 conflicts.
//  - Edit 2: kde_pre converts ONLY xb (B is 64x-reused; one-time conversion
//    amortizes). A fragments + pe are built inside kde_main from raw fp32
//    (round-10 path, proven bit-exact; 16x-redundant but ~30 VALU one-time).
//    xe16/pe arrays gone; kde_pre halves to 64 blocks.
//  - Screen tree, per-col thr, rare exp/atomicAdd/atomicMin: VERBATIM round 9.

#define KDE_N 16384
#define KDE_D 16
#define MT 32                  // rows per wave m-tile
#define MWAVES 8               // waves per block
#define MB (MT * MWAVES)       // 256 eval rows per block
#define JSPLIT 16
#define JTILES (KDE_N / 32 / JSPLIT)   // 32 j-tiles per wave
#define THR (-135.0f)          // log2-domain underflow screen
#define LOG1EM8 -18.420680743952367f   // log(1e-8)

typedef __attribute__((ext_vector_type(8)))  short   short8;
typedef __attribute__((ext_vector_type(16))) float   float16_t;

__device__ __forceinline__ unsigned short f32_to_bf16_rne(float f) {
    unsigned int u = __float_as_uint(f);
    unsigned int r = (u + 0x7FFFu + ((u >> 16) & 1u)) >> 16;
    return (unsigned short)r;
}

__device__ __forceinline__ unsigned int pack2_scaled(float a, float b) {
    const float SQSC = 12.011224664550577f;   // sqrt(100*log2e)
    return (unsigned int)f32_to_bf16_rne(a * SQSC)
         | ((unsigned int)f32_to_bf16_rne(b * SQSC) << 16);
}

// 16B-granule swizzle within each 1KB LDS tile (involution on byte offsets)
__device__ __forceinline__ int swz(int off) {
    return off ^ (((off >> 7) & 7) << 4);
}

// ---- prologue (B only): scaled bf16 cast, thr; plus S/out init per row ----
__global__ void kde_pre(const float* __restrict__ xb, float* __restrict__ S,
                        float* __restrict__ pbthr, unsigned short* __restrict__ xb16,
                        float* __restrict__ out)
{
    const int row = blockIdx.x * 256 + threadIdx.x;   // 0..16383
    const float4* s4 = (const float4*)(xb + (size_t)row * KDE_D);
    float q = 0.f;
    unsigned int w[8];
    #pragma unroll
    for (int k = 0; k < 4; ++k) {
        float4 v = s4[k];
        q += v.x*v.x + v.y*v.y + v.z*v.z + v.w*v.w;   // exact original order
        w[2*k+0] = pack2_scaled(v.x, v.y);
        w[2*k+1] = pack2_scaled(v.z, v.w);
    }
    uint4* d4 = (uint4*)(xb16 + (size_t)row * KDE_D);
    d4[0] = make_uint4(w[0], w[1], w[2], w[3]);
    d4[1] = make_uint4(w[4], w[5], w[6], w[7]);
    const float C72 = 72.134752044447963f;            // 50 * log2e
    pbthr[row] = THR + C72 * q;                       // THR - pb
    S[row] = 0.f;
    out[row] = LOG1EM8;
}

// ---- main: LDS-staged swizzled B + in-wave A/pe + MFMA + max-screen ----
__global__ __launch_bounds__(512, 8) void kde_main(
    const float* __restrict__ xe, const unsigned short* __restrict__ xb16,
    const float* __restrict__ pbthr, float* __restrict__ S, float* __restrict__ out)
{
    // smem: B bf16 [32 tiles x 1KB, swizzled] = 32768 | thr [1024 f32] = 4096 |
    //       pe exchange [8 waves x 32 f32] = 1024  => 37888 B (x4 blocks <= 160K)
    __shared__ char smem[37888];

    const int tid  = threadIdx.x;
    const int lane = tid & 63;
    const int wave = tid >> 6;                      // 0..7
    const int m0   = blockIdx.y * MB + wave * MT;
    const int jt0  = blockIdx.x * JTILES;           // j-tile base (fast dim)

    // ---- stage B-slice (32 KB) into LDS with granule swizzle ----
    {
        const char* gsrc = (const char*)xb16 + (size_t)jt0 * 32 * KDE_D * sizeof(short);
        #pragma unroll
        for (int k = 0; k < 4; ++k) {
            const int off = k * 8192 + tid * 16;    // linear global offset
            *(uint4*)(smem + swz(off)) = *(const uint4*)(gsrc + off);
        }
        if (tid < 256) {                            // thr slice, 4 KB, linear
            const int off = tid * 16;
            *(uint4*)(smem + 32768 + off) =
                *(const uint4*)((const char*)(pbthr + jt0 * 32) + off);
        }
    }

    const int col  = lane & 31;   // A row / B col / C col
    const int half = lane >> 5;   // k-half for A/B frags; row-group for C

    // ---- A fragment + pe from raw fp32, bit-identical to old kde_pre ----
    short8 af;
    {
        const float4* a4 = (const float4*)(xe + (size_t)(m0 + col) * KDE_D);
        float4 v0 = a4[0], v1 = a4[1], v2 = a4[2], v3 = a4[3];
        float q = 0.f;
        q += v0.x*v0.x + v0.y*v0.y + v0.z*v0.z + v0.w*v0.w;   // exact order
        q += v1.x*v1.x + v1.y*v1.y + v1.z*v1.z + v1.w*v1.w;
        q += v2.x*v2.x + v2.y*v2.y + v2.z*v2.z + v2.w*v2.w;
        q += v3.x*v3.x + v3.y*v3.y + v3.z*v3.z + v3.w*v3.w;
        const float T1L2E = -17.8920067984f;        // log2e * t1
        const float C72   = 72.134752044447963f;    // 50 * log2e
        const float pev = T1L2E - C72 * q;
        if (lane < 32)
            *(float*)(smem + 36864 + (wave * 32 + col) * 4) = pev;

        const float4 va = half ? v2 : v0;
        const float4 vb = half ? v3 : v1;
        union { unsigned int u[4]; short8 s; } afu;
        afu.u[0] = pack2_scaled(va.x, va.y);
        afu.u[1] = pack2_scaled(va.z, va.w);
        afu.u[2] = pack2_scaled(vb.x, vb.y);
        afu.u[3] = pack2_scaled(vb.z, vb.w);
        af = afu.s;
    }

    __syncthreads();   // B slice + thr + pe exchange resident

    // C operand = pe for the 16 C rows this lane owns:
    // row(r) = (r&3) + 8*(r>>2) + 4*half  -> quads at +0/+8/+16/+24 floats
    const float4* pq = (const float4*)(smem + 36864 + (wave * 32 + 4 * half) * 4);
    const float4 q0 = pq[0], q1 = pq[2], q2 = pq[4], q3 = pq[6];
    float16_t perv;
    perv[0]=q0.x;  perv[1]=q0.y;  perv[2]=q0.z;  perv[3]=q0.w;
    perv[4]=q1.x;  perv[5]=q1.y;  perv[6]=q1.z;  perv[7]=q1.w;
    perv[8]=q2.x;  perv[9]=q2.y;  perv[10]=q2.z; perv[11]=q2.w;
    perv[12]=q3.x; perv[13]=q3.y; perv[14]=q3.z; perv[15]=q3.w;

    const float INVN = 1.0f / (float)KDE_N;

    auto screen = [&](const float16_t& d, float thrv) {
        // max over this lane's 16 values, max3-friendly shape
        float m1 = fmaxf(fmaxf(d[0],  d[1]),  d[2]);
        float m2 = fmaxf(fmaxf(d[3],  d[4]),  d[5]);
        float m3 = fmaxf(fmaxf(d[6],  d[7]),  d[8]);
        float m4 = fmaxf(fmaxf(d[9],  d[10]), d[11]);
        float m5 = fmaxf(fmaxf(d[12], d[13]), d[14]);
        float x  = fmaxf(fmaxf(m1, m2), m3);
        float y  = fmaxf(fmaxf(m4, m5), d[15]);
        float mx = fmaxf(x, y);
        if (__any(mx > thrv)) {
            // rare: some term may exceed 2^-135
            const float pbv = THR - thrv;
            #pragma unroll
            for (int r = 0; r < 16; ++r) {
                float e = exp2f(d[r] + pbv);
                if (e != 0.f) {
                    const int row = m0 + (r & 3) + 8 * (r >> 2) + 4 * half;
                    float old  = atomicAdd(&S[row], e);
                    float cand = logf(1e-8f + (old + e) * INVN);
                    // all cands negative: float-max == uint-min on raw bits
                    atomicMin((unsigned int*)&out[row], __float_as_uint(cand));
                }
            }
        }
    };

    // ---- flat loop: swizzled read base + compile-time immediate offsets ----
    const char* bbase = smem + swz(col * 32 + half * 16);
    const char* tbase = smem + 32768 + col * 4;
    #pragma unroll 8
    for (int t = 0; t < JTILES; ++t) {
        const short8 bf   = *(const short8*)(bbase + t * 1024);
        const float  thrv = *(const float*)(tbase + t * 128);
        const float16_t d = __builtin_amdgcn_mfma_f32_32x32x16_bf16(af, bf, perv, 0, 0, 0);
        screen(d, thrv);
    }
}

extern "C" void kernel_launch(void* const* d_in, const int* in_sizes, int n_in,
                              void* d_out, int out_size, void* d_ws, size_t ws_size,
                              hipStream_t stream)
{
    const float* xe = (const float*)d_in[0];  // x_eval [16384,16] fp32
    const float* xb = (const float*)d_in[1];  // x_base [16384,16] fp32
    float* out = (float*)d_out;

    // ws layout: S[16384] | pbthr[16384] | xb16[16384*16]
    float* S     = (float*)d_ws;
    float* pbthr = S + KDE_N;
    unsigned short* xb16 = (unsigned short*)(pbthr + KDE_N);

    kde_pre<<<KDE_N / 256, 256, 0, stream>>>(xb, S, pbthr, xb16, out);   // 64 blocks
    dim3 grid(JSPLIT, KDE_N / MB);   // (16, 64) = 1024 blocks = 4/CU, resident
    kde_main<<<grid, MWAVES * 64, 0, stream>>>(xe, xb16, pbthr, S, out);
}

// Round 8
// 67.297 us; speedup vs baseline: 1.8730x; 1.0138x over previous
//
#include <hip/hip_runtime.h>
#include <math.h>

// KDE log-density: out[i] = log(1e-8 + (1/N) * sum_j exp(t1 - 50*||xe_i - xb_j||^2))
// N = 16384, D = 16, fp32 in/out.
//
// Round 13: EXACT round-9 kernel (best known, 66.6 us) + ONE change:
// XOR granule swizzle on the LDS B tiles (both staging write and read base).
//  - Round-12 post-mortem: swizzle bundled with A/pe-fusion netted -1.6 us
//    vs round 9 — the fusion overhead (16x-redundant conversion, extra
//    sync dependency, fp32 xe reads in main) ate the swizzle win. Unbundled.
//  - Counter evidence for the swizzle: SQ_LDS_BANK_CONFLICT = 2^20 per
//    kde_main dispatch = exactly 4 extra cycles per ds_read_b128 (col*32
//    row stride is an 8-way bank alias). swz: off ^= ((off>>7)&7)<<4 is an
//    involution within each 1KB tile; tile base (bits >=10) untouched, so
//    in-loop "+ t*1024" immediate offsets still work unchanged.
//  - Everything else (kde_pre, staging, prefetch-1 loop, per-col thr reads,
//    screen tree, rare exp/atomicAdd/atomicMin path): VERBATIM round 9.

#define KDE_N 16384
#define KDE_D 16
#define MT 32                  // rows per wave m-tile
#define MWAVES 8               // waves per block
#define MB (MT * MWAVES)       // 256 eval rows per block
#define JSPLIT 16
#define JTILES (KDE_N / 32 / JSPLIT)   // 32 j-tiles per wave
#define THR (-135.0f)          // log2-domain underflow screen

typedef __attribute__((ext_vector_type(8)))  short   short8;
typedef __attribute__((ext_vector_type(16))) float   float16_t;

__device__ __forceinline__ unsigned short f32_to_bf16_rne(float f) {
    unsigned int u = __float_as_uint(f);
    unsigned int r = (u + 0x7FFFu + ((u >> 16) & 1u)) >> 16;
    return (unsigned short)r;
}

// 16B-granule swizzle within each 1KB LDS tile (involution on byte offsets)
__device__ __forceinline__ int swz(int off) {
    return off ^ (((off >> 7) & 7) << 4);
}

// ---- prologue: pe / (THR - pb), scaled bf16 casts, zero S, default out ----
__global__ void kde_pre(const float* __restrict__ xe, const float* __restrict__ xb,
                        float* __restrict__ S, float* __restrict__ pe,
                        float* __restrict__ pbthr, unsigned short* __restrict__ xe16,
                        unsigned short* __restrict__ xb16, float* __restrict__ out)
{
    const int t = blockIdx.x * blockDim.x + threadIdx.x;   // 0..32767
    const int row = t & (KDE_N - 1);
    const bool isB = t >= KDE_N;
    const float* src = (isB ? xb : xe) + (size_t)row * KDE_D;
    const float4* s4 = (const float4*)src;
    const float SQSC = 12.011224664550577f;   // sqrt(100*log2e)
    float q = 0.f;
    unsigned int w[8];
    #pragma unroll
    for (int k = 0; k < 4; ++k) {
        float4 v = s4[k];
        q += v.x*v.x + v.y*v.y + v.z*v.z + v.w*v.w;
        w[2*k+0] = (unsigned int)f32_to_bf16_rne(v.x * SQSC)
                 | ((unsigned int)f32_to_bf16_rne(v.y * SQSC) << 16);
        w[2*k+1] = (unsigned int)f32_to_bf16_rne(v.z * SQSC)
                 | ((unsigned int)f32_to_bf16_rne(v.w * SQSC) << 16);
    }
    unsigned short* dst = (isB ? xb16 : xe16) + (size_t)row * KDE_D;
    uint4* d4 = (uint4*)dst;
    d4[0] = make_uint4(w[0], w[1], w[2], w[3]);
    d4[1] = make_uint4(w[4], w[5], w[6], w[7]);
    const float T1L2E  = -17.8920067984f;       // log2e * t1
    const float C72    = 72.134752044447963f;   // 50 * log2e
    const float LOG1EM8 = -18.420680743952367f; // log(1e-8)
    if (!isB) { pe[row] = T1L2E - C72 * q; S[row] = 0.f; out[row] = LOG1EM8; }
    else      { pbthr[row] = THR + C72 * q; }   // THR - pb,  pb = -C72*b2
}

// ---- main: LDS-staged B (swizzled) + MFMA + max-screen; rare path as r5 ----
__global__ __launch_bounds__(512, 8) void kde_main(
    const unsigned short* __restrict__ xe16, const unsigned short* __restrict__ xb16,
    const float* __restrict__ pe, const float* __restrict__ pbthr,
    float* __restrict__ S, float* __restrict__ out)
{
    // smem layout: B-slice bf16 [1024 rows x 32 B] = 32 KB | thr [1024 f32] = 4 KB
    __shared__ char smem[36864];

    const int tid  = threadIdx.x;
    const int lane = tid & 63;
    const int wave = tid >> 6;                      // 0..7
    const int m0   = blockIdx.y * MB + wave * MT;
    const int jt0  = blockIdx.x * JTILES;           // j-slice in fast dim

    // ---- stage B-slice (32 KB, granule-swizzled) + thr (4 KB) into LDS ----
    {
        const char* gsrc = (const char*)xb16 + (size_t)jt0 * 32 * KDE_D * sizeof(short);
        #pragma unroll
        for (int k = 0; k < 4; ++k) {
            const int off = k * 8192 + tid * 16;    // linear global offset
            *(uint4*)(smem + swz(off)) = *(const uint4*)(gsrc + off);
        }
        if (tid < 256) {                            // thr slice, linear
            const int off = tid * 16;
            *(uint4*)(smem + 32768 + off) =
                *(const uint4*)((const char*)(pbthr + jt0 * 32) + off);
        }
    }

    const int col  = lane & 31;   // A row / B col / C col
    const int half = lane >> 5;   // k-half for A/B frags; row-group for C

    // A fragment, loaded once (K=16 == D)
    const short8 af = *(const short8*)(xe16 + (size_t)(m0 + col) * KDE_D + half * 8);

    // C operand = pe for the 16 C rows this lane owns: row = (r&3)+8*(r>>2)+4*half
    float16_t perv;
    #pragma unroll
    for (int r = 0; r < 16; ++r)
        perv[r] = pe[m0 + (r & 3) + 8 * (r >> 2) + 4 * half];

    const float INVN = 1.0f / (float)KDE_N;

    auto screen = [&](const float16_t& d, float thrv) {
        // max over this lane's 16 values, max3-friendly shape
        float m1 = fmaxf(fmaxf(d[0],  d[1]),  d[2]);
        float m2 = fmaxf(fmaxf(d[3],  d[4]),  d[5]);
        float m3 = fmaxf(fmaxf(d[6],  d[7]),  d[8]);
        float m4 = fmaxf(fmaxf(d[9],  d[10]), d[11]);
        float m5 = fmaxf(fmaxf(d[12], d[13]), d[14]);
        float x  = fmaxf(fmaxf(m1, m2), m3);
        float y  = fmaxf(fmaxf(m4, m5), d[15]);
        float mx = fmaxf(x, y);
        if (__any(mx > thrv)) {
            // rare: some term may exceed 2^-135
            const float pbv = THR - thrv;
            #pragma unroll
            for (int r = 0; r < 16; ++r) {
                float e = exp2f(d[r] + pbv);
                if (e != 0.f) {
                    const int row = m0 + (r & 3) + 8 * (r >> 2) + 4 * half;
                    float old  = atomicAdd(&S[row], e);
                    float cand = logf(1e-8f + (old + e) * INVN);
                    // all cands negative: float-max == uint-min on raw bits
                    atomicMin((unsigned int*)&out[row], __float_as_uint(cand));
                }
            }
        }
    };

    __syncthreads();   // B-slice + thr resident

    // per-lane LDS base: row 'col' of a tile, k-half 'half' — swizzled;
    // "+ t*1024" tile offsets below don't touch swizzled bits (<=9)
    const int lbase = swz(col * 32 + half * 16);

    short8 bf   = *(const short8*)(smem + lbase);
    float  thrv = *(const float*)(smem + 32768 + col * 4);

    #pragma unroll 4
    for (int t = 0; t < JTILES - 1; ++t) {
        const short8 bf_n  = *(const short8*)(smem + (t + 1) * 1024 + lbase);
        const float  thr_n = *(const float*)(smem + 32768 + (t + 1) * 128 + col * 4);
        float16_t d = __builtin_amdgcn_mfma_f32_32x32x16_bf16(af, bf, perv, 0, 0, 0);
        screen(d, thrv);
        bf = bf_n; thrv = thr_n;
    }
    {   // peeled last tile (no prefetch)
        float16_t d = __builtin_amdgcn_mfma_f32_32x32x16_bf16(af, bf, perv, 0, 0, 0);
        screen(d, thrv);
    }
}

extern "C" void kernel_launch(void* const* d_in, const int* in_sizes, int n_in,
                              void* d_out, int out_size, void* d_ws, size_t ws_size,
                              hipStream_t stream)
{
    const float* xe = (const float*)d_in[0];  // x_eval [16384,16] fp32
    const float* xb = (const float*)d_in[1];  // x_base [16384,16] fp32
    float* out = (float*)d_out;

    // ws layout: S[16384] | pe[16384] | pbthr[16384] | xe16 | xb16
    float* S     = (float*)d_ws;
    float* pe    = S + KDE_N;
    float* pbthr = pe + KDE_N;
    unsigned short* xe16 = (unsigned short*)(pbthr + KDE_N);
    unsigned short* xb16 = xe16 + (size_t)KDE_N * KDE_D;

    kde_pre<<<(2 * KDE_N) / 256, 256, 0, stream>>>(xe, xb, S, pe, pbthr, xe16, xb16, out);
    dim3 grid(JSPLIT, KDE_N / MB);   // (16, 64) = 1024 blocks = 4/CU, resident
    kde_main<<<grid, MWAVES * 64, 0, stream>>>(xe16, xb16, pe, pbthr, S, out);
}